// Round 2
// 1212.684 us; speedup vs baseline: 1.9346x; 1.9346x over previous
//
#include <hip/hip_runtime.h>
#include <math.h>

typedef unsigned short u16;
typedef unsigned int u32;

#define DIM 256
#define HEADS 8
#define ATT_SCALE 0.17677669529663687f

// ---------------- counting sort by dst ----------------
__global__ void k_zero(int* hist, int n){
  int i = blockIdx.x*256 + threadIdx.x;
  if (i < n) hist[i] = 0;
}
__global__ void k_hist(const int* __restrict__ ei, int* __restrict__ hist, int ne){
  int e = blockIdx.x*256 + threadIdx.x;
  if (e < ne) atomicAdd(&hist[ei[e]], 1);
}
__global__ __launch_bounds__(256) void k_scan(const int* __restrict__ hist,
                                              int* __restrict__ rowptr,
                                              int* __restrict__ cursor, int n, int C){
  __shared__ int ssum[256];
  int t = threadIdx.x;
  int loc[64]; int sum = 0;
  for (int j=0;j<C;j++){
    int idx = t*C+j;
    int v = (idx < n) ? hist[idx] : 0;
    loc[j] = sum; sum += v;
  }
  ssum[t] = sum;
  __syncthreads();
  for (int off=1; off<256; off<<=1){
    int v = (t>=off) ? ssum[t-off] : 0;
    __syncthreads();
    ssum[t] += v;
    __syncthreads();
  }
  int base = ssum[t] - sum;  // exclusive prefix of this thread's chunk
  for (int j=0;j<C;j++){
    int idx = t*C+j;
    if (idx <= n){
      int v = base + loc[j];
      rowptr[idx] = v;
      if (idx < n) cursor[idx] = v;
    }
  }
}
__global__ void k_scatter(const int* __restrict__ ei, int* __restrict__ cursor,
                          int* __restrict__ perm, int* __restrict__ ssrc, int ne){
  int e = blockIdx.x*256 + threadIdx.x;
  if (e < ne){
    int d = ei[e];
    int pos = atomicAdd(&cursor[d], 1);
    perm[pos] = e;
    ssrc[pos] = ei[ne + e];
  }
}

// ---------------- qkv GEMM: C[N,768] = x[N,256] @ [Wq;Wk;Wv]^T ----------------
// BM=64, BN=64, BK=32, 256 threads, 4x4 microtile per thread.
// LDS staged K-major ([k][m]/[k][n]) so both fragments are ds_read_b128.
__global__ __launch_bounds__(256) void k_qkv_gemm(const float* __restrict__ x,
    const float* __restrict__ Wq, const float* __restrict__ Wk, const float* __restrict__ Wv,
    float* __restrict__ qkv, int N){
  __shared__ float As[32][64];   // [k][m]
  __shared__ float Bs[32][64];   // [k][n]
  int t = threadIdx.x;
  int i0 = blockIdx.x * 64;
  int bj = blockIdx.y;                          // 0..11 over 768 output cols
  const float* W = (bj < 4) ? Wq : (bj < 8) ? Wk : Wv;
  int j0 = (bj & 3) * 64;
  // staging map: thread t loads 2 float4 of A and 2 of B per K-chunk
  int lr = t >> 2;            // row 0..63
  int lk = (t & 3) * 8;       // k offset 0,8,16,24
  int arow = i0 + lr; if (arow >= N) arow = N - 1;   // clamp; results unused
  const float* ap = x + (size_t)arow*256 + lk;
  const float* bp = W + (size_t)(j0 + lr)*256 + lk;
  int tx = t & 15, ty = t >> 4;
  float acc[4][4] = {};
  for (int k0 = 0; k0 < 256; k0 += 32){
    float4 a0 = *(const float4*)(ap + k0);
    float4 a1 = *(const float4*)(ap + k0 + 4);
    float4 b0 = *(const float4*)(bp + k0);
    float4 b1 = *(const float4*)(bp + k0 + 4);
    __syncthreads();   // previous iteration's reads done
    As[lk+0][lr]=a0.x; As[lk+1][lr]=a0.y; As[lk+2][lr]=a0.z; As[lk+3][lr]=a0.w;
    As[lk+4][lr]=a1.x; As[lk+5][lr]=a1.y; As[lk+6][lr]=a1.z; As[lk+7][lr]=a1.w;
    Bs[lk+0][lr]=b0.x; Bs[lk+1][lr]=b0.y; Bs[lk+2][lr]=b0.z; Bs[lk+3][lr]=b0.w;
    Bs[lk+4][lr]=b1.x; Bs[lk+5][lr]=b1.y; Bs[lk+6][lr]=b1.z; Bs[lk+7][lr]=b1.w;
    __syncthreads();
    #pragma unroll
    for (int k = 0; k < 32; k++){
      float4 a = *(const float4*)&As[k][ty*4];
      float4 b = *(const float4*)&Bs[k][tx*4];
      float av[4] = {a.x, a.y, a.z, a.w};
      float bv[4] = {b.x, b.y, b.z, b.w};
      #pragma unroll
      for (int m = 0; m < 4; m++)
        #pragma unroll
        for (int n = 0; n < 4; n++)
          acc[m][n] += av[m] * bv[n];
    }
  }
  #pragma unroll
  for (int m = 0; m < 4; m++){
    int row = i0 + ty*4 + m;
    if (row < N){
      float4 o; o.x = acc[m][0]; o.y = acc[m][1]; o.z = acc[m][2]; o.w = acc[m][3];
      *(float4*)(qkv + (size_t)row*768 + bj*64 + tx*4) = o;
    }
  }
}

// ---------------- transpose Wev, Wout (256x256 each) for coalesced k_out reads ----------------
__global__ __launch_bounds__(256) void k_transpose2(const float* __restrict__ Wev,
    const float* __restrict__ Wout, float* __restrict__ WevT, float* __restrict__ WoutT){
  __shared__ float tile[32][33];
  const float* src = blockIdx.z ? Wout : Wev;
  float*       dst = blockIdx.z ? WoutT : WevT;
  int bx = blockIdx.x * 32, by = blockIdx.y * 32;
  int tx = threadIdx.x & 31, ty4 = (threadIdx.x >> 5) * 4;
  #pragma unroll
  for (int r = 0; r < 4; r++)
    tile[ty4+r][tx] = src[(size_t)(by + ty4 + r)*256 + bx + tx];
  __syncthreads();
  #pragma unroll
  for (int r = 0; r < 4; r++)
    dst[(size_t)(bx + ty4 + r)*256 + by + tx] = tile[tx][ty4+r];
}

// ---------------- per-node: logits, GELU-MLP, segment softmax ----------------
__global__ __launch_bounds__(256) void k_attn(
    const float* __restrict__ qkv, const float* __restrict__ Wek,
    const float* __restrict__ edges, const float* __restrict__ Wexp, const float* __restrict__ Wsq,
    const int* __restrict__ rowptr, const int* __restrict__ perm, const int* __restrict__ ssrc,
    float* __restrict__ zbuf, float* __restrict__ attn_out){
  __shared__ float g_s[8][260];
  __shared__ float q_s[256];
  __shared__ float we_s[128];
  __shared__ float wsq_s[128];
  __shared__ float es_s[8][256];
  __shared__ int  src_s[8];
  __shared__ float z_s[8][8];
  __shared__ float t_s[8][16];
  __shared__ float z2_s[8][8];
  __shared__ float m_s[8];
  __shared__ float s_s[8];
  int i = blockIdx.x, t = threadIdx.x;
  int rs = rowptr[i], re = rowptr[i+1];
  q_s[t] = qkv[(size_t)i*768 + t];
  if (t < 128) we_s[t] = Wexp[t];
  else         wsq_s[t-128] = Wsq[t-128];
  __syncthreads();
  #pragma unroll
  for (int h=0;h<8;h++){
    float a = 0.f;
    #pragma unroll
    for (int d=0; d<32; d++){
      a += q_s[h*32+d] * Wek[(size_t)(h*32+d)*256 + t];
    }
    g_s[h][t] = a;
  }
  __syncthreads();
  int h = t>>5, s = t&31;
  float mreg = -3.0e38f;
  for (int p0 = rs; p0 < re; p0 += 8){
    int nE = min(8, re-p0);
    for (int ee=0; ee<nE; ee++){
      int er = perm[p0+ee];
      es_s[ee][t] = edges[(size_t)er*256 + t];
    }
    if (t < nE) src_s[t] = ssrc[p0+t];
    __syncthreads();
    for (int ee=0; ee<nE; ee++){
      float partial = 0.f;
      #pragma unroll
      for (int j=0;j<8;j++) partial += es_s[ee][s*8+j]*g_s[h][s*8+j];
      partial += q_s[h*32+s] * qkv[(size_t)src_s[ee]*768 + 256 + h*32 + s];
      #pragma unroll
      for (int off=16; off>=1; off>>=1)
        partial += __shfl_xor(partial, off, 32);
      if (s == 0) z_s[ee][h] = partial * ATT_SCALE;
    }
    __syncthreads();
    if (t < nE*16){
      int ee = t>>4, j = t&15;
      float u = 0.f;
      #pragma unroll
      for (int hh=0;hh<8;hh++) u += z_s[ee][hh]*we_s[j*8+hh];
      u = 0.5f*u*(1.f + erff(u*0.70710678118654752f));  // exact GELU
      t_s[ee][j] = u;
    }
    __syncthreads();
    if (t < nE*8){
      int ee = t>>3, hh = t&7;
      float z2 = 0.f;
      #pragma unroll
      for (int j=0;j<16;j++) z2 += t_s[ee][j]*wsq_s[hh*16+j];
      z2_s[ee][hh] = z2;
      zbuf[(size_t)(p0+ee)*8 + hh] = z2;
    }
    __syncthreads();
    if (t < 8){
      for (int ee=0;ee<nE;ee++) mreg = fmaxf(mreg, z2_s[ee][t]);
    }
    __syncthreads();
  }
  if (t < 8) m_s[t] = mreg;
  __syncthreads();
  if (t < 8){
    float sr = 0.f;
    for (int p=rs; p<re; p++) sr += expf(zbuf[(size_t)p*8 + t] - m_s[t]);
    s_s[t] = sr;
  }
  __syncthreads();
  {
    int pp = t>>3, hh = t&7;
    for (int p = rs+pp; p < re; p += 32){
      float z = zbuf[(size_t)p*8 + hh];
      float a = expf(z - m_s[hh]) / (s_s[hh] + 1e-16f);
      zbuf[(size_t)p*8 + hh] = a;
      attn_out[(size_t)perm[p]*8 + hh] = a;
    }
  }
}

// ---------------- per-node: value path + Wev + Wout + bias ----------------
// COALESCED=true: Wv_/Wo_ are transposed copies, read WT[c*256+t] (lane-coalesced).
// COALESCED=false: Wv_/Wo_ are the original row-major weights, read W[t*256+c].
template<bool COALESCED>
__global__ __launch_bounds__(256) void k_out(
    const float* __restrict__ qkv, const float* __restrict__ edges,
    const float* __restrict__ Wv_, const float* __restrict__ Wo_, const float* __restrict__ bout,
    const int* __restrict__ rowptr, const int* __restrict__ perm, const int* __restrict__ ssrc,
    const float* __restrict__ zbuf, float* __restrict__ out_d){
  __shared__ float es_s[8][256];
  __shared__ float a_s[8][8];
  __shared__ int  src_s[8];
  __shared__ float t_s[8][260];
  __shared__ float o_s[256];
  int i = blockIdx.x, t = threadIdx.x;
  int rs = rowptr[i], re = rowptr[i+1];
  int hc = t>>5;
  float tacc[8];
  #pragma unroll
  for (int j=0;j<8;j++) tacc[j]=0.f;
  float vacc = 0.f;
  for (int p0=rs; p0<re; p0+=8){
    int nE = min(8, re-p0);
    for (int ee=0; ee<nE; ee++){
      int er = perm[p0+ee];
      es_s[ee][t] = edges[(size_t)er*256 + t];
    }
    if (t < nE*8) a_s[t>>3][t&7] = zbuf[(size_t)(p0 + (t>>3))*8 + (t&7)];
    if (t < nE)   src_s[t] = ssrc[p0+t];
    __syncthreads();
    for (int ee=0; ee<nE; ee++){
      float ef = es_s[ee][t];
      #pragma unroll
      for (int j=0;j<8;j++) tacc[j] += a_s[ee][j]*ef;
      vacc += a_s[ee][hc] * qkv[(size_t)src_s[ee]*768 + 512 + t];
    }
    __syncthreads();
  }
  #pragma unroll
  for (int j=0;j<8;j++) t_s[j][t] = tacc[j];
  __syncthreads();
  float vtot = vacc;
  {
    const float* tp = &t_s[hc][0];
    if (COALESCED){
      for (int c=0;c<256;c++) vtot += Wv_[(size_t)c*256 + t]*tp[c];
    } else {
      const float* wp = Wv_ + (size_t)t*256;
      for (int c=0;c<256;c++) vtot += wp[c]*tp[c];
    }
  }
  o_s[t] = vtot;
  __syncthreads();
  float oacc = bout[t];
  if (COALESCED){
    for (int c=0;c<256;c++) oacc += Wo_[(size_t)c*256 + t]*o_s[c];
  } else {
    const float* wp = Wo_ + (size_t)t*256;
    for (int c=0;c<256;c++) oacc += wp[c]*o_s[c];
  }
  out_d[(size_t)i*256 + t] = oacc;
}

extern "C" void kernel_launch(void* const* d_in, const int* in_sizes, int n_in,
                              void* d_out, int out_size, void* d_ws, size_t ws_size,
                              hipStream_t stream){
  const float* x     = (const float*)d_in[0];
  const float* edges = (const float*)d_in[1];
  const int*   ei    = (const int*)d_in[2];
  const float* Wq    = (const float*)d_in[3];
  const float* Wk    = (const float*)d_in[4];
  const float* Wv    = (const float*)d_in[5];
  const float* Wek   = (const float*)d_in[6];
  const float* Wev   = (const float*)d_in[7];
  const float* Wexp  = (const float*)d_in[8];
  const float* Wsq   = (const float*)d_in[9];
  const float* Wout  = (const float*)d_in[10];
  const float* bout  = (const float*)d_in[11];

  const int N = in_sizes[0] / DIM;        // x is [N, 256]
  const int E = in_sizes[2] / 2;          // edge_index is [2, E]

  // ws layout, 256B-aligned, fp32 everywhere. ~43.7 MB core + optional 512KB transposes.
  char* base = (char*)d_ws;
  size_t off = 0;
  auto align256 = [](size_t v){ return (v + 255) & ~(size_t)255; };
  float* qkv    = (float*)(base + off); off += align256((size_t)N*768*4);
  float* zbuf   = (float*)(base + off); off += align256((size_t)E*8*4);
  int*   rowptr = (int*)(base + off);   off += align256((size_t)(N+1)*4);
  int*   cursor = (int*)(base + off);   off += align256((size_t)N*4);
  int*   hist   = (int*)(base + off);   off += align256((size_t)N*4);
  int*   perm   = (int*)(base + off);   off += align256((size_t)E*4);
  int*   ssrc   = (int*)(base + off);   off += align256((size_t)E*4);
  // optional transposed weights (only used if the workspace can hold them)
  size_t off_tr = off;
  float* WevT   = (float*)(base + off_tr);
  float* WoutT  = (float*)(base + off_tr + align256((size_t)256*256*4));
  size_t off_end = off_tr + 2*align256((size_t)256*256*4);
  const bool use_tr = (off_end <= ws_size);

  float* out_d  = (float*)d_out;                  // [N,256] fp32
  float* attn_d = out_d + (size_t)N*DIM;          // [E,8] fp32

  int C = N/256 + 1;                              // per-thread chunk in k_scan
  if (C > 64) C = 64;

  k_zero<<<(N+255)/256, 256, 0, stream>>>(hist, N);
  k_hist<<<(E+255)/256, 256, 0, stream>>>(ei, hist, E);
  k_scan<<<1, 256, 0, stream>>>(hist, rowptr, cursor, N, C);
  k_scatter<<<(E+255)/256, 256, 0, stream>>>(ei, cursor, perm, ssrc, E);
  if (use_tr)
    k_transpose2<<<dim3(8,8,2), 256, 0, stream>>>(Wev, Wout, WevT, WoutT);
  dim3 g_qkv((N+63)/64, 12);
  k_qkv_gemm<<<g_qkv, 256, 0, stream>>>(x, Wq, Wk, Wv, qkv, N);
  k_attn<<<N, 256, 0, stream>>>(qkv, Wek, edges, Wexp, Wsq,
                                rowptr, perm, ssrc, zbuf, attn_d);
  if (use_tr)
    k_out<true><<<N, 256, 0, stream>>>(qkv, edges, WevT, WoutT, bout,
                                       rowptr, perm, ssrc, zbuf, out_d);
  else
    k_out<false><<<N, 256, 0, stream>>>(qkv, edges, Wev, Wout, bout,
                                        rowptr, perm, ssrc, zbuf, out_d);
}

// Round 3
// 1087.783 us; speedup vs baseline: 2.1568x; 1.1148x over previous
//
#include <hip/hip_runtime.h>
#include <math.h>

typedef unsigned short u16;
typedef unsigned int u32;

#define DIM 256
#define HEADS 8
#define ATT_SCALE 0.17677669529663687f

// ---------------- counting sort by dst ----------------
__global__ void k_zero(int* hist, int n){
  int i = blockIdx.x*256 + threadIdx.x;
  if (i < n) hist[i] = 0;
}
__global__ void k_hist(const int* __restrict__ ei, int* __restrict__ hist, int ne){
  int e = blockIdx.x*256 + threadIdx.x;
  if (e < ne) atomicAdd(&hist[ei[e]], 1);
}
__global__ __launch_bounds__(256) void k_scan(const int* __restrict__ hist,
                                              int* __restrict__ rowptr,
                                              int* __restrict__ cursor, int n, int C){
  __shared__ int ssum[256];
  int t = threadIdx.x;
  int loc[64]; int sum = 0;
  for (int j=0;j<C;j++){
    int idx = t*C+j;
    int v = (idx < n) ? hist[idx] : 0;
    loc[j] = sum; sum += v;
  }
  ssum[t] = sum;
  __syncthreads();
  for (int off=1; off<256; off<<=1){
    int v = (t>=off) ? ssum[t-off] : 0;
    __syncthreads();
    ssum[t] += v;
    __syncthreads();
  }
  int base = ssum[t] - sum;  // exclusive prefix of this thread's chunk
  for (int j=0;j<C;j++){
    int idx = t*C+j;
    if (idx <= n){
      int v = base + loc[j];
      rowptr[idx] = v;
      if (idx < n) cursor[idx] = v;
    }
  }
}
__global__ void k_scatter(const int* __restrict__ ei, int* __restrict__ cursor,
                          int* __restrict__ perm, int* __restrict__ ssrc, int ne){
  int e = blockIdx.x*256 + threadIdx.x;
  if (e < ne){
    int d = ei[e];
    int pos = atomicAdd(&cursor[d], 1);
    perm[pos] = e;
    ssrc[pos] = ei[ne + e];
  }
}

// ---------------- qkv GEMM: C[N,768] = x[N,256] @ [Wq;Wk;Wv]^T ----------------
__global__ __launch_bounds__(256) void k_qkv_gemm(const float* __restrict__ x,
    const float* __restrict__ Wq, const float* __restrict__ Wk, const float* __restrict__ Wv,
    float* __restrict__ qkv, int N){
  __shared__ float As[32][64];   // [k][m]
  __shared__ float Bs[32][64];   // [k][n]
  int t = threadIdx.x;
  int i0 = blockIdx.x * 64;
  int bj = blockIdx.y;                          // 0..11 over 768 output cols
  const float* W = (bj < 4) ? Wq : (bj < 8) ? Wk : Wv;
  int j0 = (bj & 3) * 64;
  int lr = t >> 2;            // row 0..63
  int lk = (t & 3) * 8;       // k offset 0,8,16,24
  int arow = i0 + lr; if (arow >= N) arow = N - 1;   // clamp; results unused
  const float* ap = x + (size_t)arow*256 + lk;
  const float* bp = W + (size_t)(j0 + lr)*256 + lk;
  int tx = t & 15, ty = t >> 4;
  float acc[4][4] = {};
  for (int k0 = 0; k0 < 256; k0 += 32){
    float4 a0 = *(const float4*)(ap + k0);
    float4 a1 = *(const float4*)(ap + k0 + 4);
    float4 b0 = *(const float4*)(bp + k0);
    float4 b1 = *(const float4*)(bp + k0 + 4);
    __syncthreads();   // previous iteration's reads done
    As[lk+0][lr]=a0.x; As[lk+1][lr]=a0.y; As[lk+2][lr]=a0.z; As[lk+3][lr]=a0.w;
    As[lk+4][lr]=a1.x; As[lk+5][lr]=a1.y; As[lk+6][lr]=a1.z; As[lk+7][lr]=a1.w;
    Bs[lk+0][lr]=b0.x; Bs[lk+1][lr]=b0.y; Bs[lk+2][lr]=b0.z; Bs[lk+3][lr]=b0.w;
    Bs[lk+4][lr]=b1.x; Bs[lk+5][lr]=b1.y; Bs[lk+6][lr]=b1.z; Bs[lk+7][lr]=b1.w;
    __syncthreads();
    #pragma unroll
    for (int k = 0; k < 32; k++){
      float4 a = *(const float4*)&As[k][ty*4];
      float4 b = *(const float4*)&Bs[k][tx*4];
      float av[4] = {a.x, a.y, a.z, a.w};
      float bv[4] = {b.x, b.y, b.z, b.w};
      #pragma unroll
      for (int m = 0; m < 4; m++)
        #pragma unroll
        for (int n = 0; n < 4; n++)
          acc[m][n] += av[m] * bv[n];
    }
  }
  #pragma unroll
  for (int m = 0; m < 4; m++){
    int row = i0 + ty*4 + m;
    if (row < N){
      float4 o; o.x = acc[m][0]; o.y = acc[m][1]; o.z = acc[m][2]; o.w = acc[m][3];
      *(float4*)(qkv + (size_t)row*768 + bj*64 + tx*4) = o;
    }
  }
}

// ---------------- transpose Wev, Wout (256x256 each) ----------------
__global__ __launch_bounds__(256) void k_transpose2(const float* __restrict__ Wev,
    const float* __restrict__ Wout, float* __restrict__ WevT, float* __restrict__ WoutT){
  __shared__ float tile[32][33];
  const float* src = blockIdx.z ? Wout : Wev;
  float*       dst = blockIdx.z ? WoutT : WevT;
  int bx = blockIdx.x * 32, by = blockIdx.y * 32;
  int tx = threadIdx.x & 31, ty4 = (threadIdx.x >> 5) * 4;
  #pragma unroll
  for (int r = 0; r < 4; r++)
    tile[ty4+r][tx] = src[(size_t)(by + ty4 + r)*256 + bx + tx];
  __syncthreads();
  #pragma unroll
  for (int r = 0; r < 4; r++)
    dst[(size_t)(bx + ty4 + r)*256 + by + tx] = tile[tx][ty4+r];
}

// ---------------- fused: logits + GELU-MLP + ONLINE softmax + value path + Wev/Wout ----------------
// Reads edges exactly once. Running (m,s) per head; tacc/vacc rescaled by exp(m_old-m_new).
// zbuf holds raw z2 logits; attn_out finalized in-block at the end.
template<bool COALESCED>
__global__ __launch_bounds__(256) void k_fused(
    const float* __restrict__ qkv, const float* __restrict__ Wek,
    const float* __restrict__ edges, const float* __restrict__ Wexp, const float* __restrict__ Wsq,
    const float* __restrict__ Wv_, const float* __restrict__ Wo_, const float* __restrict__ bout,
    const int* __restrict__ rowptr, const int* __restrict__ perm, const int* __restrict__ ssrc,
    float* __restrict__ zbuf, float* __restrict__ attn_out, float* __restrict__ out_d){
  __shared__ float g_s[8][260];
  __shared__ float q_s[256];
  __shared__ float we_s[128];
  __shared__ float wsq_s[128];
  __shared__ float pool[8][260];   // edge tile during loop; t_s in tail
  __shared__ int   src_s[8];
  __shared__ float z_s[8][8];
  __shared__ float t16_s[8][16];
  __shared__ float z2_s[8][8];
  __shared__ float a_s[8][8];
  __shared__ float m_s[8];
  __shared__ float s_s[8];
  __shared__ float r_s[8];
  __shared__ float o_s[256];

  int i = blockIdx.x, t = threadIdx.x;
  int rs = rowptr[i], re = rowptr[i+1];
  int h = t>>5, s = t&31;

  q_s[t] = qkv[(size_t)i*768 + t];
  if (t < 128) we_s[t] = Wexp[t];
  else         wsq_s[t-128] = Wsq[t-128];
  if (t < 8){ m_s[t] = -3.0e38f; s_s[t] = 0.f; }
  __syncthreads();
  // g_s[h][c] = sum_d q[h,d]*Wek[h*32+d, c]
  #pragma unroll
  for (int hh=0; hh<8; hh++){
    float a = 0.f;
    #pragma unroll
    for (int d=0; d<32; d++)
      a += q_s[hh*32+d] * Wek[(size_t)(hh*32+d)*256 + t];
    g_s[hh][t] = a;
  }

  // register prefetch of edge rows (float4): thread t covers flat float4 idx t and t+256
  const float4* e4 = (const float4*)edges;
  int r0 = t>>6, c40 = t&63;          // rows 0..3
  int r1 = r0 + 4;                    // rows 4..7
  float4 c0, c1;
  if (re - rs >= 8){
    int ea = perm[rs + r0], eb = perm[rs + r1];
    c0 = e4[(size_t)ea*64 + c40];
    c1 = e4[(size_t)eb*64 + c40];
  }
  __syncthreads();   // g_s ready

  float tacc[8];
  #pragma unroll
  for (int j=0;j<8;j++) tacc[j]=0.f;
  float vacc = 0.f;

  for (int p0 = rs; p0 < re; p0 += 8){
    int nE = min(8, re-p0);
    // ---- stage edge tile (pool free: end-of-iter barrier or first iter) ----
    if (nE == 8){
      *(float4*)&pool[r0][c40*4] = c0;
      *(float4*)&pool[r1][c40*4] = c1;
      if (re - (p0+8) >= 8){          // prefetch next full chunk
        int ea = perm[p0+8 + r0], eb = perm[p0+8 + r1];
        c0 = e4[(size_t)ea*64 + c40];
        c1 = e4[(size_t)eb*64 + c40];
      }
    } else {
      for (int ee=0; ee<nE; ee++){
        int er = perm[p0+ee];
        pool[ee][t] = edges[(size_t)er*256 + t];
      }
    }
    if (t < nE) src_s[t] = ssrc[p0+t];
    __syncthreads();

    // ---- pre-issue k and v gathers (rows coalesced across 256 threads) ----
    float kreg[8], vreg[8];
    for (int ee=0; ee<nE; ee++) kreg[ee] = qkv[(size_t)src_s[ee]*768 + 256 + t];
    for (int ee=0; ee<nE; ee++) vreg[ee] = qkv[(size_t)src_s[ee]*768 + 512 + t];

    // ---- z[ee][h]: conflict-free stride-32 dot + coalesced k term ----
    for (int ee=0; ee<nE; ee++){
      float partial = q_s[t] * kreg[ee];
      #pragma unroll
      for (int j=0;j<8;j++) partial += pool[ee][j*32+s]*g_s[h][j*32+s];
      #pragma unroll
      for (int off=16; off>=1; off>>=1)
        partial += __shfl_xor(partial, off, 32);
      if (s == 0) z_s[ee][h] = partial * ATT_SCALE;
    }
    __syncthreads();

    // ---- head-expand + exact GELU ----
    if (t < nE*16){
      int ee = t>>4, j = t&15;
      float u = 0.f;
      #pragma unroll
      for (int hh=0;hh<8;hh++) u += z_s[ee][hh]*we_s[j*8+hh];
      u = 0.5f*u*(1.f + erff(u*0.70710678118654752f));
      t16_s[ee][j] = u;
    }
    __syncthreads();

    // ---- squeeze -> z2; store raw logits for attn finalize ----
    if (t < nE*8){
      int ee = t>>3, hh = t&7;
      float z2 = 0.f;
      #pragma unroll
      for (int j=0;j<16;j++) z2 += t16_s[ee][j]*wsq_s[hh*16+j];
      z2_s[ee][hh] = z2;
      zbuf[(size_t)(p0+ee)*8 + hh] = z2;
    }
    __syncthreads();

    // ---- online softmax head update ----
    if (t < 8){
      float cm = -3.0e38f;
      for (int ee=0; ee<nE; ee++) cm = fmaxf(cm, z2_s[ee][t]);
      float mo = m_s[t];
      float mn = fmaxf(mo, cm);
      float r  = expf(mo - mn);
      float sa = 0.f;
      for (int ee=0; ee<nE; ee++){
        float a = expf(z2_s[ee][t] - mn);
        a_s[ee][t] = a; sa += a;
      }
      s_s[t] = s_s[t]*r + sa;
      m_s[t] = mn;
      r_s[t] = r;
    }
    __syncthreads();

    // ---- rescale + accumulate value and edge-feature sums ----
    float rh = r_s[h];
    vacc *= rh;
    for (int ee=0; ee<nE; ee++) vacc += a_s[ee][h]*vreg[ee];
    #pragma unroll
    for (int j=0;j<8;j++) tacc[j] *= r_s[j];
    for (int ee=0; ee<nE; ee++){
      float ef = pool[ee][t];
      #pragma unroll
      for (int j=0;j<8;j++) tacc[j] += a_s[ee][j]*ef;
    }
    __syncthreads();   // pool/z2/a free for next chunk
  }

  // ---- tail: normalize, Wev, Wout, bias ----
  #pragma unroll
  for (int j=0;j<8;j++) tacc[j] = tacc[j] / (s_s[j] + 1e-16f);
  float vnorm = vacc / (s_s[h] + 1e-16f);
  #pragma unroll
  for (int j=0;j<8;j++) pool[j][t] = tacc[j];
  __syncthreads();

  // attn_out finalize (independent of the FMA loops below; overlaps)
  {
    int pp = t>>3, hh = t&7;
    float mh = m_s[hh], shv = s_s[hh] + 1e-16f;
    for (int p = rs+pp; p < re; p += 32)
      attn_out[(size_t)perm[p]*8 + hh] = expf(zbuf[(size_t)p*8 + hh] - mh) / shv;
  }

  float vtot = vnorm;
  {
    const float* tp = &pool[h][0];
    if (COALESCED){
      for (int c=0;c<256;c++) vtot += Wv_[(size_t)c*256 + t]*tp[c];
    } else {
      const float* wp = Wv_ + (size_t)t*256;
      for (int c=0;c<256;c++) vtot += wp[c]*tp[c];
    }
  }
  o_s[t] = vtot;
  __syncthreads();
  float oacc = bout[t];
  if (COALESCED){
    for (int c=0;c<256;c++) oacc += Wo_[(size_t)c*256 + t]*o_s[c];
  } else {
    const float* wp = Wo_ + (size_t)t*256;
    for (int c=0;c<256;c++) oacc += wp[c]*o_s[c];
  }
  out_d[(size_t)i*256 + t] = oacc;
}

extern "C" void kernel_launch(void* const* d_in, const int* in_sizes, int n_in,
                              void* d_out, int out_size, void* d_ws, size_t ws_size,
                              hipStream_t stream){
  const float* x     = (const float*)d_in[0];
  const float* edges = (const float*)d_in[1];
  const int*   ei    = (const int*)d_in[2];
  const float* Wq    = (const float*)d_in[3];
  const float* Wk    = (const float*)d_in[4];
  const float* Wv    = (const float*)d_in[5];
  const float* Wek   = (const float*)d_in[6];
  const float* Wev   = (const float*)d_in[7];
  const float* Wexp  = (const float*)d_in[8];
  const float* Wsq   = (const float*)d_in[9];
  const float* Wout  = (const float*)d_in[10];
  const float* bout  = (const float*)d_in[11];

  const int N = in_sizes[0] / DIM;        // x is [N, 256]
  const int E = in_sizes[2] / 2;          // edge_index is [2, E]

  char* base = (char*)d_ws;
  size_t off = 0;
  auto align256 = [](size_t v){ return (v + 255) & ~(size_t)255; };
  float* qkv    = (float*)(base + off); off += align256((size_t)N*768*4);
  float* zbuf   = (float*)(base + off); off += align256((size_t)E*8*4);
  int*   rowptr = (int*)(base + off);   off += align256((size_t)(N+1)*4);
  int*   cursor = (int*)(base + off);   off += align256((size_t)N*4);
  int*   hist   = (int*)(base + off);   off += align256((size_t)N*4);
  int*   perm   = (int*)(base + off);   off += align256((size_t)E*4);
  int*   ssrc   = (int*)(base + off);   off += align256((size_t)E*4);
  size_t off_tr = off;
  float* WevT   = (float*)(base + off_tr);
  float* WoutT  = (float*)(base + off_tr + align256((size_t)256*256*4));
  size_t off_end = off_tr + 2*align256((size_t)256*256*4);
  const bool use_tr = (off_end <= ws_size);

  float* out_d  = (float*)d_out;                  // [N,256] fp32
  float* attn_d = out_d + (size_t)N*DIM;          // [E,8] fp32

  int C = N/256 + 1;
  if (C > 64) C = 64;

  k_zero<<<(N+255)/256, 256, 0, stream>>>(hist, N);
  k_hist<<<(E+255)/256, 256, 0, stream>>>(ei, hist, E);
  k_scan<<<1, 256, 0, stream>>>(hist, rowptr, cursor, N, C);
  k_scatter<<<(E+255)/256, 256, 0, stream>>>(ei, cursor, perm, ssrc, E);
  if (use_tr)
    k_transpose2<<<dim3(8,8,2), 256, 0, stream>>>(Wev, Wout, WevT, WoutT);
  dim3 g_qkv((N+63)/64, 12);
  k_qkv_gemm<<<g_qkv, 256, 0, stream>>>(x, Wq, Wk, Wv, qkv, N);
  if (use_tr)
    k_fused<true><<<N, 256, 0, stream>>>(qkv, Wek, edges, Wexp, Wsq,
                                         WevT, WoutT, bout,
                                         rowptr, perm, ssrc, zbuf, attn_d, out_d);
  else
    k_fused<false><<<N, 256, 0, stream>>>(qkv, Wek, edges, Wexp, Wsq,
                                          Wev, Wout, bout,
                                          rowptr, perm, ssrc, zbuf, attn_d, out_d);
}